// Round 1
// baseline (752.281 us; speedup 1.0000x reference)
//
#include <hip/hip_runtime.h>

// ---- problem constants ----
#define SEQ     2048
#define HIDDEN  4544          // 71 * 64
#define NHEAD   71
#define HD      64
#define QKV_OUT 4672          // (71+2)*64
#define QKV_PAD 4864          // 19*256
#define HID_PAD 4608          // 18*256

typedef __bf16    bf16;
typedef _Float16  f16;
typedef __bf16    bf16x8 __attribute__((ext_vector_type(8)));
typedef __bf16    bf16x4 __attribute__((ext_vector_type(4)));
typedef _Float16  f16x4  __attribute__((ext_vector_type(4)));
typedef float     f32x4  __attribute__((ext_vector_type(4)));

// async global->LDS, 16B per lane. ldsbase must be wave-uniform; HW adds lane*16B.
__device__ inline void gl2lds16(const void* g, void* ldsbase) {
  __builtin_amdgcn_global_load_lds(
      (const __attribute__((address_space(1))) unsigned int*)g,
      (__attribute__((address_space(3))) unsigned int*)ldsbase,
      16, 0, 0);
}

// ---------------- fp32 -> bf16 convert, with zero row-padding ----------------
// out has nrows_pad rows of ncols; rows >= nrows are zero-filled.
__global__ void cvt_pad_k(const float* __restrict__ in, bf16* __restrict__ out,
                          int ncols4, int nrows, int n4tot) {
  int i = blockIdx.x * blockDim.x + threadIdx.x;
  if (i >= n4tot) return;
  int row = i / ncols4;
  bf16x4 o;
  if (row < nrows) {
    float4 f = ((const float4*)in)[i];
    o[0] = (bf16)f.x; o[1] = (bf16)f.y; o[2] = (bf16)f.z; o[3] = (bf16)f.w;
  } else {
    o[0] = o[1] = o[2] = o[3] = (bf16)0.f;
  }
  *(bf16x4*)(out + (size_t)i * 4) = o;
}

// ---------------- 8-phase-pipelined bt-GEMM ----------------
// C[M x Nmat] = A[M x K] * B[Nrows_pad x K]^T,  M % 256 == 0, K % 32 == 0,
// B padded with zero rows to gridDim.y*256. 256x256 C-tile, 512 threads
// (8 waves, 2Mx4N, per-wave 128x64). Ring of 4 K-tile LDS buffers (K-tile=32),
// counted vmcnt(6) (never 0), XOR slot-swizzle u^(row&3) on stage-source + read.
__global__ __launch_bounds__(512) void gemm8p_k(const bf16* __restrict__ A,
                                                const bf16* __restrict__ B,
                                                float* __restrict__ C,
                                                int K, int Nmat, int ldc) {
  __shared__ bf16 lA[4][256 * 32];   // [ring slot][row*32 + k], 64B rows
  __shared__ bf16 lB[4][256 * 32];
  const int t = threadIdx.x;
  const int lane = t & 63, w = t >> 6;
  const int qi = lane & 15, grp = lane >> 4;
  const int wm = w >> 2, wn = w & 3;              // 2 x 4 wave grid
  const int m0 = blockIdx.x * 256, n0 = blockIdx.y * 256;

  // stage source: thread t owns LDS bytes t*16 of a 128-row half-tile:
  // row = t>>2 (0..127), slot u = t&3. Global k-offset pre-swizzled u^(row&3)
  // so that the swizzled LDS read below recovers the linear data.
  const int srow  = t >> 2;
  const int sk8   = ((t & 3) ^ (srow & 3)) * 8;   // elems
  const bf16* gA = A + (size_t)(m0 + srow) * K + sk8;
  const bf16* gB = B + (size_t)(n0 + srow) * K + sk8;
  const size_t halfR = (size_t)128 * K;           // 128-row half stride (elems)

  const int NK = K >> 5;                          // K-tiles of 32
  // read-side swizzled k-slot (lane-constant: row%4 == qi%4 for all fragments)
  const int xsl = ((grp ^ (qi & 3)) * 8);

  f32x4 acc[8][4] = {};
  bf16x8 bfr[4];

  // prologue: fully stage K-tiles 0 and 1 (8 wave-loads)
  {
    gl2lds16(gA,               &lA[0][w * 512]);
    gl2lds16(gA + halfR,       &lA[0][4096 + w * 512]);
    gl2lds16(gB,               &lB[0][w * 512]);
    gl2lds16(gB + halfR,       &lB[0][4096 + w * 512]);
    gl2lds16(gA + 32,          &lA[1][w * 512]);
    gl2lds16(gA + halfR + 32,  &lA[1][4096 + w * 512]);
    gl2lds16(gB + 32,          &lB[1][w * 512]);
    gl2lds16(gB + halfR + 32,  &lB[1][4096 + w * 512]);
  }

  for (int kt = 0; kt < NK; ++kt) {
    const int s = kt & 3;
    const int sn = (kt + 2) & 3;                  // stage target slot
    const int kf = (kt + 2 < NK ? kt + 2 : NK - 1) << 5;  // clamped prefetch k

    // ---- phase 0: stage A(kt+2); vmcnt(6); barrier; read A[0..3]+B; 16 MFMA ----
    gl2lds16(gA + kf,          &lA[sn][w * 512]);
    gl2lds16(gA + halfR + kf,  &lA[sn][4096 + w * 512]);
    // ledger: issued = 4*kt + 10 wave-loads; vmcnt(6) => oldest 4*kt+4 landed
    // = all of K-tile kt. Barrier makes it cross-wave.
    asm volatile("s_waitcnt vmcnt(6)" ::: "memory");
    __builtin_amdgcn_s_barrier();
    asm volatile("" ::: "memory");                // no LDS-read hoist above barrier
    bf16x8 afr[4];
#pragma unroll
    for (int i = 0; i < 4; ++i)
      afr[i] = *(const bf16x8*)&lA[s][(wm * 128 + i * 16 + qi) * 32 + xsl];
#pragma unroll
    for (int j = 0; j < 4; ++j)
      bfr[j] = *(const bf16x8*)&lB[s][(wn * 64 + j * 16 + qi) * 32 + xsl];
    __builtin_amdgcn_s_setprio(1);
#pragma unroll
    for (int i = 0; i < 4; ++i)
#pragma unroll
      for (int j = 0; j < 4; ++j)
        acc[i][j] = __builtin_amdgcn_mfma_f32_16x16x32_bf16(afr[i], bfr[j], acc[i][j], 0, 0, 0);
    __builtin_amdgcn_s_setprio(0);
    __builtin_amdgcn_s_barrier();

    // ---- phase 1: stage B(kt+2); barrier; read A[4..7]; 16 MFMA (reuse bfr) ----
    gl2lds16(gB + kf,          &lB[sn][w * 512]);
    gl2lds16(gB + halfR + kf,  &lB[sn][4096 + w * 512]);
    __builtin_amdgcn_s_barrier();
#pragma unroll
    for (int i = 0; i < 4; ++i)
      afr[i] = *(const bf16x8*)&lA[s][(wm * 128 + (i + 4) * 16 + qi) * 32 + xsl];
    __builtin_amdgcn_s_setprio(1);
#pragma unroll
    for (int i = 0; i < 4; ++i)
#pragma unroll
      for (int j = 0; j < 4; ++j)
        acc[i + 4][j] = __builtin_amdgcn_mfma_f32_16x16x32_bf16(afr[i], bfr[j], acc[i + 4][j], 0, 0, 0);
    __builtin_amdgcn_s_setprio(0);
    __builtin_amdgcn_s_barrier();
  }

  // ---- epilogue: C-write (cols beyond Nmat are from zero-padded B rows; guarded) ----
#pragma unroll
  for (int i = 0; i < 8; ++i) {
    const int row = m0 + wm * 128 + i * 16 + grp * 4;
#pragma unroll
    for (int j = 0; j < 4; ++j) {
      const int col = n0 + wn * 64 + j * 16 + qi;
      if (col < Nmat) {
#pragma unroll
        for (int r = 0; r < 4; ++r)
          C[(size_t)(row + r) * ldc + col] = acc[i][j][r];
      }
    }
  }
}

// ---------------- RoPE for Q (scale 1/8 folded in) + cos/sin tables ----------------
__global__ __launch_bounds__(256) void rope_q_k(const float* __restrict__ fused,
                                                bf16* __restrict__ Qb,
                                                float* __restrict__ cs_tab,
                                                float* __restrict__ sn_tab) {
  const int s = blockIdx.x, t = threadIdx.x;
  __shared__ float cs[64], sn[64];
  if (t < 64) {
    int i = t & 31;
    double invf = pow(10000.0, -(double)i / 32.0);
    double ang = (double)s * invf;
    float c = (float)cos(ang), n = (float)sin(ang);
    cs[t] = c; sn[t] = n;
    cs_tab[s * 64 + t] = c;
    sn_tab[s * 64 + t] = n;
  }
  __syncthreads();
  const float* row = fused + (size_t)s * QKV_OUT;
  for (int e = t; e < HIDDEN; e += 256) {
    int d = e & 63;
    float x = row[e], xp = row[e ^ 32];
    float rot = (d < 32) ? -xp : xp;
    Qb[(size_t)s * HIDDEN + e] = (bf16)((x * cs[d] + rot * sn[d]) * 0.125f);
  }
}

// ---------------- K (roped) and V -> MFMA-operand-ordered global layouts ----------------
__global__ __launch_bounds__(64) void kvprep_k(const float* __restrict__ fused,
                                               const float* __restrict__ cs_tab,
                                               const float* __restrict__ sn_tab,
                                               bf16* __restrict__ Kf,
                                               f16* __restrict__ Vf) {
  const int t16 = blockIdx.x, lane = threadIdx.x;
  const int qi = lane & 15, grp = lane >> 4;
  const int s = t16 * 16 + qi;
  const float* krow = fused + (size_t)s * QKV_OUT + NHEAD * 64;
  const float* cs = cs_tab + s * 64;
  const float* sn = sn_tab + s * 64;
#pragma unroll
  for (int half = 0; half < 2; ++half) {
    bf16x8 o;
    const int d0 = half * 32 + grp * 8;
#pragma unroll
    for (int j = 0; j < 8; ++j) {
      int d = d0 + j;
      float x = krow[d], xp = krow[d ^ 32];
      float rot = (d < 32) ? -xp : xp;
      o[j] = (bf16)(x * cs[d] + rot * sn[d]);
    }
    *(bf16x8*)&Kf[(t16 * 2 + half) * 512 + lane * 8] = o;
  }
#pragma unroll
  for (int tt = 0; tt < 4; ++tt) {
    f16x4 o;
#pragma unroll
    for (int j = 0; j < 4; ++j)
      o[j] = (f16)fused[(size_t)(t16 * 16 + grp * 4 + j) * QKV_OUT + (NHEAD + 1) * 64 + tt * 16 + qi];
    *(f16x4*)&Vf[t16 * 1024 + tt * 256 + lane * 4] = o;
  }
}

// ---------------- causal MQA flash attention: 1 wave = (head, 32 q rows) ----------------
__global__ __launch_bounds__(64) void attn_k(const bf16* __restrict__ Qb,
                                             const bf16* __restrict__ Kf,
                                             const f16*  __restrict__ Vf,
                                             bf16* __restrict__ Ao) {
  __shared__ float fl[2 * 16 * 68];
  const int h = blockIdx.y;
  const int b32 = gridDim.x - 1 - blockIdx.x;   // big blocks first
  const int lane = threadIdx.x;
  const int qi = lane & 15, grp = lane >> 4;
  const int q0 = b32 * 32;
  const int lastT = b32 >> 1;

  bf16x8 qf[2][2];
#pragma unroll
  for (int qq = 0; qq < 2; ++qq) {
    const bf16* qb = Qb + (size_t)(q0 + qq * 16 + qi) * HIDDEN + h * 64 + grp * 8;
    qf[qq][0] = *(const bf16x8*)qb;
    qf[qq][1] = *(const bf16x8*)(qb + 32);
  }

  f32x4 o[2][4] = {};
  float l[2] = {0.f, 0.f};

  for (int kb = 0; kb <= lastT; ++kb) {
    const bf16* kfp = Kf + (size_t)kb * 4096 + lane * 8;
    bf16x8 kf[4][2];
#pragma unroll
    for (int kk = 0; kk < 4; ++kk) {
      kf[kk][0] = *(const bf16x8*)(kfp + kk * 1024);
      kf[kk][1] = *(const bf16x8*)(kfp + kk * 1024 + 512);
    }
    f32x4 s4[2][4];
#pragma unroll
    for (int qq = 0; qq < 2; ++qq)
#pragma unroll
      for (int kk = 0; kk < 4; ++kk) {
        f32x4 z = {};
        s4[qq][kk] = __builtin_amdgcn_mfma_f32_16x16x32_bf16(kf[kk][0], qf[qq][0], z, 0, 0, 0);
        s4[qq][kk] = __builtin_amdgcn_mfma_f32_16x16x32_bf16(kf[kk][1], qf[qq][1], s4[qq][kk], 0, 0, 0);
      }
    const f16* vfp = Vf + (size_t)kb * 4096 + lane * 4;
    f16x4 vf[4][4];
#pragma unroll
    for (int kk = 0; kk < 4; ++kk)
#pragma unroll
      for (int tt = 0; tt < 4; ++tt)
        vf[kk][tt] = *(const f16x4*)(vfp + kk * 1024 + tt * 256);

    if (kb == lastT) {
      const int dq = q0 - kb * 64 + qi;
#pragma unroll
      for (int qq = 0; qq < 2; ++qq)
#pragma unroll
        for (int kk = 0; kk < 4; ++kk)
#pragma unroll
          for (int r = 0; r < 4; ++r)
            if (kk * 16 + grp * 4 + r > dq + qq * 16) s4[qq][kk][r] = -1e30f;
    }
    f16x4 pf[2][4];
#pragma unroll
    for (int qq = 0; qq < 2; ++qq) {
      float ls = 0.f;
#pragma unroll
      for (int kk = 0; kk < 4; ++kk) {
        float p0 = __expf(s4[qq][kk][0]), p1 = __expf(s4[qq][kk][1]);
        float p2 = __expf(s4[qq][kk][2]), p3 = __expf(s4[qq][kk][3]);
        ls += (p0 + p1) + (p2 + p3);
        pf[qq][kk][0] = (f16)p0; pf[qq][kk][1] = (f16)p1;
        pf[qq][kk][2] = (f16)p2; pf[qq][kk][3] = (f16)p3;
      }
      l[qq] += ls;
    }
#pragma unroll
    for (int qq = 0; qq < 2; ++qq)
#pragma unroll
      for (int tt = 0; tt < 4; ++tt)
#pragma unroll
        for (int kk = 0; kk < 4; ++kk)
          o[qq][tt] = __builtin_amdgcn_mfma_f32_16x16x16f16(pf[qq][kk], vf[kk][tt], o[qq][tt], 0, 0, 0);
  }

#pragma unroll
  for (int qq = 0; qq < 2; ++qq) {
    float lq = l[qq];
    lq += __shfl_xor(lq, 16);
    lq += __shfl_xor(lq, 32);
    const float inv = 1.0f / lq;
    const float i0 = __shfl(inv, grp * 4 + 0);
    const float i1 = __shfl(inv, grp * 4 + 1);
    const float i2 = __shfl(inv, grp * 4 + 2);
    const float i3 = __shfl(inv, grp * 4 + 3);
    float* flq = fl + qq * 1088;
#pragma unroll
    for (int tt = 0; tt < 4; ++tt) {
      flq[(grp * 4 + 0) * 68 + tt * 16 + qi] = o[qq][tt][0] * i0;
      flq[(grp * 4 + 1) * 68 + tt * 16 + qi] = o[qq][tt][1] * i1;
      flq[(grp * 4 + 2) * 68 + tt * 16 + qi] = o[qq][tt][2] * i2;
      flq[(grp * 4 + 3) * 68 + tt * 16 + qi] = o[qq][tt][3] * i3;
    }
  }
  __syncthreads();
  const int row = lane >> 2, c0 = (lane & 3) * 16;
#pragma unroll
  for (int qq = 0; qq < 2; ++qq) {
    const float* flq = fl + qq * 1088;
    bf16x8 w0, w1;
#pragma unroll
    for (int j = 0; j < 8; ++j) {
      w0[j] = (bf16)flq[row * 68 + c0 + j];
      w1[j] = (bf16)flq[row * 68 + c0 + 8 + j];
    }
    bf16* ob = Ao + (size_t)(q0 + qq * 16 + row) * HIDDEN + h * 64 + c0;
    *(bf16x8*)ob = w0;
    *(bf16x8*)(ob + 8) = w1;
  }
}

// ---------------- launcher ----------------
extern "C" void kernel_launch(void* const* d_in, const int* in_sizes, int n_in,
                              void* d_out, int out_size, void* d_ws, size_t ws_size,
                              hipStream_t stream) {
  (void)in_sizes; (void)n_in; (void)out_size; (void)ws_size;
  const float* hs   = (const float*)d_in[0];
  const float* wqkv = (const float*)d_in[1];
  const float* wd   = (const float*)d_in[2];
  float* out = (float*)d_out;

  char* ws = (char*)d_ws;
  size_t off = 0;
  auto alloc = [&](size_t b) -> char* {
    char* p = ws + off;
    off += (b + 255) & ~(size_t)255;
    return p;
  };
  bf16* Xb     = (bf16*)alloc((size_t)SEQ * HIDDEN * 2);
  bf16* Wqb    = (bf16*)alloc((size_t)QKV_PAD * HIDDEN * 2);   // zero-padded rows
  bf16* Wdb    = (bf16*)alloc((size_t)HID_PAD * HIDDEN * 2);   // zero-padded rows
  float* fused = (float*)alloc((size_t)SEQ * QKV_OUT * 4);
  bf16* Qb     = (bf16*)alloc((size_t)SEQ * HIDDEN * 2);
  bf16* Kf     = (bf16*)alloc((size_t)(SEQ / 16) * 1024 * 2);
  f16*  Vf     = (f16*)alloc((size_t)(SEQ / 16) * 1024 * 2);
  float* cs_tab = (float*)alloc((size_t)SEQ * 64 * 4);
  float* sn_tab = (float*)alloc((size_t)SEQ * 64 * 4);
  bf16* Ao     = (bf16*)fused;  // fused dead after rope/kvprep -> reuse

  const int NC4 = HIDDEN / 4;   // 1136
  {
    int n4 = SEQ * NC4;
    cvt_pad_k<<<(n4 + 255) / 256, 256, 0, stream>>>(hs, Xb, NC4, SEQ, n4);
    n4 = QKV_PAD * NC4;
    cvt_pad_k<<<(n4 + 255) / 256, 256, 0, stream>>>(wqkv, Wqb, NC4, QKV_OUT, n4);
    n4 = HID_PAD * NC4;
    cvt_pad_k<<<(n4 + 255) / 256, 256, 0, stream>>>(wd, Wdb, NC4, HIDDEN, n4);
  }
  gemm8p_k<<<dim3(SEQ / 256, QKV_PAD / 256), 512, 0, stream>>>(
      Xb, Wqb, fused, HIDDEN, QKV_OUT, QKV_OUT);
  rope_q_k<<<SEQ, 256, 0, stream>>>(fused, Qb, cs_tab, sn_tab);
  kvprep_k<<<SEQ / 16, 64, 0, stream>>>(fused, cs_tab, sn_tab, Kf, Vf);
  attn_k<<<dim3(SEQ / 32, NHEAD), 64, 0, stream>>>(Qb, Kf, Vf, Ao);
  gemm8p_k<<<dim3(SEQ / 256, HID_PAD / 256), 512, 0, stream>>>(
      Ao, Wdb, out, HIDDEN, HIDDEN, HIDDEN);
}

// Round 2
// 626.055 us; speedup vs baseline: 1.2016x; 1.2016x over previous
//
#include <hip/hip_runtime.h>

// ---- problem constants ----
#define SEQ     2048
#define HIDDEN  4544          // 71 * 64
#define NHEAD   71
#define HD      64
#define QKV_OUT 4672          // (71+2)*64
#define QKV_PAD 4864          // 19*256
#define HID_PAD 4608          // 18*256

typedef __bf16    bf16;
typedef _Float16  f16;
typedef __bf16    bf16x8 __attribute__((ext_vector_type(8)));
typedef __bf16    bf16x4 __attribute__((ext_vector_type(4)));
typedef _Float16  f16x4  __attribute__((ext_vector_type(4)));
typedef float     f32x4  __attribute__((ext_vector_type(4)));

// async global->LDS, 16B per lane. ldsbase must be wave-uniform; HW adds lane*16B.
__device__ inline void gl2lds16(const void* g, void* ldsbase) {
  __builtin_amdgcn_global_load_lds(
      (const __attribute__((address_space(1))) unsigned int*)g,
      (__attribute__((address_space(3))) unsigned int*)ldsbase,
      16, 0, 0);
}

// ---------------- fp32 -> bf16 convert, with zero row-padding ----------------
__global__ void cvt_pad_k(const float* __restrict__ in, bf16* __restrict__ out,
                          int ncols4, int nrows, int n4tot) {
  int i = blockIdx.x * blockDim.x + threadIdx.x;
  if (i >= n4tot) return;
  int row = i / ncols4;
  bf16x4 o;
  if (row < nrows) {
    float4 f = ((const float4*)in)[i];
    o[0] = (bf16)f.x; o[1] = (bf16)f.y; o[2] = (bf16)f.z; o[3] = (bf16)f.w;
  } else {
    o[0] = o[1] = o[2] = o[3] = (bf16)0.f;
  }
  *(bf16x4*)(out + (size_t)i * 4) = o;
}

// LDS tile layout (256 rows x 64 cols bf16, st_16x32-style subtiled+swizzled):
// elem(R, ce) = (R>>4)*1024 + (ce>>5)*512 + (R&15)*32 + ((ce&31) ^ (((R>>3)&1)<<4))
__device__ inline int ldsaddr(int R, int ks, int grp) {
  return (R >> 4) * 1024 + ks * 512 + (R & 15) * 32 + ((grp * 8) ^ (((R >> 3) & 1) << 4));
}

// stage one 64-row chunk (8KB = 4 subtile-pairs) of a 256x64 tile.
// dest is LINEAR in thread order (HW requirement); source address carries the
// inverse swizzle so that swizzled reads recover linear data (G21 both-sides rule).
__device__ inline void stage64s(const bf16* mat, int gr0, int kc, int K,
                                bf16* region, int t, int w) {
  const int row = ((t >> 7) << 4) + ((t >> 2) & 15);
  const int ce  = (((t >> 6) & 1) << 5) + ((((t & 3) << 3)) ^ (((t >> 5) & 1) << 4));
  gl2lds16(mat + (size_t)(gr0 + row) * K + kc + ce, region + w * 512);
}

// ---------------- 4-phase-per-K-tile pipelined bt-GEMM (m201 template port) ----
// C[M x Nmat] = A[M x K] * B[Npad x K]^T,  M%256==0, K%64==0, B zero-row-padded.
// 256x256 tile, 512 threads (8 waves 2Mx4N, per-wave 128x64), BK=64, 2 LDS bufs.
// Phase: {ds_reads; stage 1 half-tile; barrier; lgkm(0); setprio; 16 MFMA; barrier}.
// vmcnt(4) once per K-tile (never 0): 2 half-tiles stay in flight.
__global__ __launch_bounds__(512) void gemm8p_k(const bf16* __restrict__ A,
                                                const bf16* __restrict__ B,
                                                float* __restrict__ C,
                                                int K, int Nmat, int ldc) {
  __shared__ bf16 lA[2][256 * 64];
  __shared__ bf16 lB[2][256 * 64];
  const int t = threadIdx.x;
  const int lane = t & 63, w = t >> 6;
  const int qi = lane & 15, grp = lane >> 4;
  const int wm = w >> 2, wn = w & 3;

  // XCD-aware block swizzle (both call sites have nwg % 8 == 0)
  const int gx = gridDim.x;
  const int nwg = gx * gridDim.y;
  const int orig = blockIdx.y * gx + blockIdx.x;
  const int swz = (orig & 7) * (nwg >> 3) + (orig >> 3);
  const int m0 = (swz % gx) * 256;
  const int n0 = (swz / gx) * 256;

  const int NK = K >> 6;

  // prologue: stage T0 {A-H0,A-H1,B-H0,B-H1}, T1 {B-H0,B-H1}  (12 wave-loads)
  stage64s(A, m0 +   0, 0, K, &lA[0][0],        t, w);
  stage64s(A, m0 +  64, 0, K, &lA[0][64 * 64],  t, w);
  stage64s(A, m0 + 128, 0, K, &lA[0][128 * 64], t, w);
  stage64s(A, m0 + 192, 0, K, &lA[0][192 * 64], t, w);
  stage64s(B, n0 +   0, 0, K, &lB[0][0],        t, w);
  stage64s(B, n0 +  64, 0, K, &lB[0][64 * 64],  t, w);
  stage64s(B, n0 + 128, 0, K, &lB[0][128 * 64], t, w);
  stage64s(B, n0 + 192, 0, K, &lB[0][192 * 64], t, w);
  const int k1 = (NK > 1 ? 1 : 0) << 6;
  stage64s(B, n0 +   0, k1, K, &lB[1][0],        t, w);
  stage64s(B, n0 +  64, k1, K, &lB[1][64 * 64],  t, w);
  stage64s(B, n0 + 128, k1, K, &lB[1][128 * 64], t, w);
  stage64s(B, n0 + 192, k1, K, &lB[1][192 * 64], t, w);
  // T0 fully landed (T1's 2 B-halves may remain in flight)
  asm volatile("s_waitcnt vmcnt(4)" ::: "memory");
  __builtin_amdgcn_s_barrier();

  f32x4 acc[8][4] = {};
  bf16x8 a[4][2], b0[2][2], b1[2][2];

  for (int kt = 0; kt < NK; ++kt) {
    const int c = kt & 1;
    const int bA = c ^ 1;
    const int kA = (kt + 1 < NK ? kt + 1 : NK - 1) << 6;   // T_{kt+1} A staging
    const int kB = (kt + 2 < NK ? kt + 2 : NK - 1) << 6;   // T_{kt+2} B staging

    // ---- phase 0 (mh0,nh0): read a(mh0) 8 + b0 4; stage T_{kt+1} A-H0 ----
#pragma unroll
    for (int i = 0; i < 4; ++i) {
      const int R = wm * 128 + i * 16 + qi;
      a[i][0] = *(const bf16x8*)&lA[c][ldsaddr(R, 0, grp)];
      a[i][1] = *(const bf16x8*)&lA[c][ldsaddr(R, 1, grp)];
    }
#pragma unroll
    for (int j = 0; j < 2; ++j) {
      const int R = wn * 64 + j * 16 + qi;
      b0[j][0] = *(const bf16x8*)&lB[c][ldsaddr(R, 0, grp)];
      b0[j][1] = *(const bf16x8*)&lB[c][ldsaddr(R, 1, grp)];
    }
    stage64s(A, m0 +  0, kA, K, &lA[bA][0],       t, w);
    stage64s(A, m0 + 64, kA, K, &lA[bA][64 * 64], t, w);
    asm volatile("" ::: "memory");
    __builtin_amdgcn_s_barrier();
    asm volatile("s_waitcnt lgkmcnt(0)" ::: "memory");
    __builtin_amdgcn_s_setprio(1);
#pragma unroll
    for (int i = 0; i < 4; ++i)
#pragma unroll
      for (int j = 0; j < 2; ++j) {
        acc[i][j] = __builtin_amdgcn_mfma_f32_16x16x32_bf16(a[i][0], b0[j][0], acc[i][j], 0, 0, 0);
        acc[i][j] = __builtin_amdgcn_mfma_f32_16x16x32_bf16(a[i][1], b0[j][1], acc[i][j], 0, 0, 0);
      }
    __builtin_amdgcn_s_setprio(0);
    __builtin_amdgcn_s_barrier();

    // ---- phase 1 (mh0,nh1): read b1 4; stage T_{kt+1} A-H1 ----
#pragma unroll
    for (int j = 0; j < 2; ++j) {
      const int R = wn * 64 + 32 + j * 16 + qi;
      b1[j][0] = *(const bf16x8*)&lB[c][ldsaddr(R, 0, grp)];
      b1[j][1] = *(const bf16x8*)&lB[c][ldsaddr(R, 1, grp)];
    }
    stage64s(A, m0 + 128, kA, K, &lA[bA][128 * 64], t, w);
    stage64s(A, m0 + 192, kA, K, &lA[bA][192 * 64], t, w);
    asm volatile("" ::: "memory");
    __builtin_amdgcn_s_barrier();
    asm volatile("s_waitcnt lgkmcnt(0)" ::: "memory");
    __builtin_amdgcn_s_setprio(1);
#pragma unroll
    for (int i = 0; i < 4; ++i)
#pragma unroll
      for (int j = 0; j < 2; ++j) {
        acc[i][2 + j] = __builtin_amdgcn_mfma_f32_16x16x32_bf16(a[i][0], b1[j][0], acc[i][2 + j], 0, 0, 0);
        acc[i][2 + j] = __builtin_amdgcn_mfma_f32_16x16x32_bf16(a[i][1], b1[j][1], acc[i][2 + j], 0, 0, 0);
      }
    __builtin_amdgcn_s_setprio(0);
    __builtin_amdgcn_s_barrier();

    // ---- phase 2 (mh1,nh1): read a(mh1) 8; stage T_{kt+2} B-H0 (buffer c; B reads of
    //      tile kt all drained at ph1's lgkm before its end barrier -> WAR-safe) ----
#pragma unroll
    for (int i = 0; i < 4; ++i) {
      const int R = wm * 128 + 64 + i * 16 + qi;
      a[i][0] = *(const bf16x8*)&lA[c][ldsaddr(R, 0, grp)];
      a[i][1] = *(const bf16x8*)&lA[c][ldsaddr(R, 1, grp)];
    }
    stage64s(B, n0 +  0, kB, K, &lB[c][0],       t, w);
    stage64s(B, n0 + 64, kB, K, &lB[c][64 * 64], t, w);
    asm volatile("" ::: "memory");
    __builtin_amdgcn_s_barrier();
    asm volatile("s_waitcnt lgkmcnt(0)" ::: "memory");
    __builtin_amdgcn_s_setprio(1);
#pragma unroll
    for (int i = 0; i < 4; ++i)
#pragma unroll
      for (int j = 0; j < 2; ++j) {
        acc[4 + i][2 + j] = __builtin_amdgcn_mfma_f32_16x16x32_bf16(a[i][0], b1[j][0], acc[4 + i][2 + j], 0, 0, 0);
        acc[4 + i][2 + j] = __builtin_amdgcn_mfma_f32_16x16x32_bf16(a[i][1], b1[j][1], acc[4 + i][2 + j], 0, 0, 0);
      }
    __builtin_amdgcn_s_setprio(0);
    __builtin_amdgcn_s_barrier();

    // ---- phase 3 (mh1,nh0): no ds_reads (a,b0 live); stage T_{kt+2} B-H1; vmcnt(4)
    //      ledger: issued = 12 + 8*(kt+1); vmcnt(4) => all of T_{kt+1} landed. ----
    stage64s(B, n0 + 128, kB, K, &lB[c][128 * 64], t, w);
    stage64s(B, n0 + 192, kB, K, &lB[c][192 * 64], t, w);
    asm volatile("s_waitcnt vmcnt(4)" ::: "memory");
    __builtin_amdgcn_s_barrier();
    __builtin_amdgcn_s_setprio(1);
#pragma unroll
    for (int i = 0; i < 4; ++i)
#pragma unroll
      for (int j = 0; j < 2; ++j) {
        acc[4 + i][j] = __builtin_amdgcn_mfma_f32_16x16x32_bf16(a[i][0], b0[j][0], acc[4 + i][j], 0, 0, 0);
        acc[4 + i][j] = __builtin_amdgcn_mfma_f32_16x16x32_bf16(a[i][1], b0[j][1], acc[4 + i][j], 0, 0, 0);
      }
    __builtin_amdgcn_s_setprio(0);
    __builtin_amdgcn_s_barrier();
  }

  // ---- epilogue: C-write (cols >= Nmat are from zero-padded B rows; guarded) ----
#pragma unroll
  for (int mi = 0; mi < 8; ++mi) {
    const int row = m0 + wm * 128 + (mi >> 2) * 64 + (mi & 3) * 16 + grp * 4;
#pragma unroll
    for (int nj = 0; nj < 4; ++nj) {
      const int col = n0 + wn * 64 + (nj >> 1) * 32 + (nj & 1) * 16 + qi;
      if (col < Nmat) {
#pragma unroll
        for (int r = 0; r < 4; ++r)
          C[(size_t)(row + r) * ldc + col] = acc[mi][nj][r];
      }
    }
  }
}

// ---------------- RoPE for Q (scale 1/8 folded in) + cos/sin tables ----------------
__global__ __launch_bounds__(256) void rope_q_k(const float* __restrict__ fused,
                                                bf16* __restrict__ Qb,
                                                float* __restrict__ cs_tab,
                                                float* __restrict__ sn_tab) {
  const int s = blockIdx.x, t = threadIdx.x;
  __shared__ float cs[64], sn[64];
  if (t < 64) {
    int i = t & 31;
    double invf = pow(10000.0, -(double)i / 32.0);
    double ang = (double)s * invf;
    float c = (float)cos(ang), n = (float)sin(ang);
    cs[t] = c; sn[t] = n;
    cs_tab[s * 64 + t] = c;
    sn_tab[s * 64 + t] = n;
  }
  __syncthreads();
  const float* row = fused + (size_t)s * QKV_OUT;
  for (int e = t; e < HIDDEN; e += 256) {
    int d = e & 63;
    float x = row[e], xp = row[e ^ 32];
    float rot = (d < 32) ? -xp : xp;
    Qb[(size_t)s * HIDDEN + e] = (bf16)((x * cs[d] + rot * sn[d]) * 0.125f);
  }
}

// ---------------- K (roped) and V -> MFMA-operand-ordered global layouts ----------------
__global__ __launch_bounds__(64) void kvprep_k(const float* __restrict__ fused,
                                               const float* __restrict__ cs_tab,
                                               const float* __restrict__ sn_tab,
                                               bf16* __restrict__ Kf,
                                               f16* __restrict__ Vf) {
  const int t16 = blockIdx.x, lane = threadIdx.x;
  const int qi = lane & 15, grp = lane >> 4;
  const int s = t16 * 16 + qi;
  const float* krow = fused + (size_t)s * QKV_OUT + NHEAD * 64;
  const float* cs = cs_tab + s * 64;
  const float* sn = sn_tab + s * 64;
#pragma unroll
  for (int half = 0; half < 2; ++half) {
    bf16x8 o;
    const int d0 = half * 32 + grp * 8;
#pragma unroll
    for (int j = 0; j < 8; ++j) {
      int d = d0 + j;
      float x = krow[d], xp = krow[d ^ 32];
      float rot = (d < 32) ? -xp : xp;
      o[j] = (bf16)(x * cs[d] + rot * sn[d]);
    }
    *(bf16x8*)&Kf[(t16 * 2 + half) * 512 + lane * 8] = o;
  }
#pragma unroll
  for (int tt = 0; tt < 4; ++tt) {
    f16x4 o;
#pragma unroll
    for (int j = 0; j < 4; ++j)
      o[j] = (f16)fused[(size_t)(t16 * 16 + grp * 4 + j) * QKV_OUT + (NHEAD + 1) * 64 + tt * 16 + qi];
    *(f16x4*)&Vf[t16 * 1024 + tt * 256 + lane * 4] = o;
  }
}

// ---------------- causal MQA flash attention: 1 wave = (head, 32 q rows) ----------------
__global__ __launch_bounds__(64) void attn_k(const bf16* __restrict__ Qb,
                                             const bf16* __restrict__ Kf,
                                             const f16*  __restrict__ Vf,
                                             bf16* __restrict__ Ao) {
  __shared__ float fl[2 * 16 * 68];
  const int h = blockIdx.y;
  const int b32 = gridDim.x - 1 - blockIdx.x;   // big blocks first
  const int lane = threadIdx.x;
  const int qi = lane & 15, grp = lane >> 4;
  const int q0 = b32 * 32;
  const int lastT = b32 >> 1;

  bf16x8 qf[2][2];
#pragma unroll
  for (int qq = 0; qq < 2; ++qq) {
    const bf16* qb = Qb + (size_t)(q0 + qq * 16 + qi) * HIDDEN + h * 64 + grp * 8;
    qf[qq][0] = *(const bf16x8*)qb;
    qf[qq][1] = *(const bf16x8*)(qb + 32);
  }

  f32x4 o[2][4] = {};
  float l[2] = {0.f, 0.f};

  for (int kb = 0; kb <= lastT; ++kb) {
    const bf16* kfp = Kf + (size_t)kb * 4096 + lane * 8;
    bf16x8 kf[4][2];
#pragma unroll
    for (int kk = 0; kk < 4; ++kk) {
      kf[kk][0] = *(const bf16x8*)(kfp + kk * 1024);
      kf[kk][1] = *(const bf16x8*)(kfp + kk * 1024 + 512);
    }
    f32x4 s4[2][4];
#pragma unroll
    for (int qq = 0; qq < 2; ++qq)
#pragma unroll
      for (int kk = 0; kk < 4; ++kk) {
        f32x4 z = {};
        s4[qq][kk] = __builtin_amdgcn_mfma_f32_16x16x32_bf16(kf[kk][0], qf[qq][0], z, 0, 0, 0);
        s4[qq][kk] = __builtin_amdgcn_mfma_f32_16x16x32_bf16(kf[kk][1], qf[qq][1], s4[qq][kk], 0, 0, 0);
      }
    const f16* vfp = Vf + (size_t)kb * 4096 + lane * 4;
    f16x4 vf[4][4];
#pragma unroll
    for (int kk = 0; kk < 4; ++kk)
#pragma unroll
      for (int tt = 0; tt < 4; ++tt)
        vf[kk][tt] = *(const f16x4*)(vfp + kk * 1024 + tt * 256);

    if (kb == lastT) {
      const int dq = q0 - kb * 64 + qi;
#pragma unroll
      for (int qq = 0; qq < 2; ++qq)
#pragma unroll
        for (int kk = 0; kk < 4; ++kk)
#pragma unroll
          for (int r = 0; r < 4; ++r)
            if (kk * 16 + grp * 4 + r > dq + qq * 16) s4[qq][kk][r] = -1e30f;
    }
    f16x4 pf[2][4];
#pragma unroll
    for (int qq = 0; qq < 2; ++qq) {
      float ls = 0.f;
#pragma unroll
      for (int kk = 0; kk < 4; ++kk) {
        float p0 = __expf(s4[qq][kk][0]), p1 = __expf(s4[qq][kk][1]);
        float p2 = __expf(s4[qq][kk][2]), p3 = __expf(s4[qq][kk][3]);
        ls += (p0 + p1) + (p2 + p3);
        pf[qq][kk][0] = (f16)p0; pf[qq][kk][1] = (f16)p1;
        pf[qq][kk][2] = (f16)p2; pf[qq][kk][3] = (f16)p3;
      }
      l[qq] += ls;
    }
#pragma unroll
    for (int qq = 0; qq < 2; ++qq)
#pragma unroll
      for (int tt = 0; tt < 4; ++tt)
#pragma unroll
        for (int kk = 0; kk < 4; ++kk)
          o[qq][tt] = __builtin_amdgcn_mfma_f32_16x16x16f16(pf[qq][kk], vf[kk][tt], o[qq][tt], 0, 0, 0);
  }

#pragma unroll
  for (int qq = 0; qq < 2; ++qq) {
    float lq = l[qq];
    lq += __shfl_xor(lq, 16);
    lq += __shfl_xor(lq, 32);
    const float inv = 1.0f / lq;
    const float i0 = __shfl(inv, grp * 4 + 0);
    const float i1 = __shfl(inv, grp * 4 + 1);
    const float i2 = __shfl(inv, grp * 4 + 2);
    const float i3 = __shfl(inv, grp * 4 + 3);
    float* flq = fl + qq * 1088;
#pragma unroll
    for (int tt = 0; tt < 4; ++tt) {
      flq[(grp * 4 + 0) * 68 + tt * 16 + qi] = o[qq][tt][0] * i0;
      flq[(grp * 4 + 1) * 68 + tt * 16 + qi] = o[qq][tt][1] * i1;
      flq[(grp * 4 + 2) * 68 + tt * 16 + qi] = o[qq][tt][2] * i2;
      flq[(grp * 4 + 3) * 68 + tt * 16 + qi] = o[qq][tt][3] * i3;
    }
  }
  __syncthreads();
  const int row = lane >> 2, c0 = (lane & 3) * 16;
#pragma unroll
  for (int qq = 0; qq < 2; ++qq) {
    const float* flq = fl + qq * 1088;
    bf16x8 w0, w1;
#pragma unroll
    for (int j = 0; j < 8; ++j) {
      w0[j] = (bf16)flq[row * 68 + c0 + j];
      w1[j] = (bf16)flq[row * 68 + c0 + 8 + j];
    }
    bf16* ob = Ao + (size_t)(q0 + qq * 16 + row) * HIDDEN + h * 64 + c0;
    *(bf16x8*)ob = w0;
    *(bf16x8*)(ob + 8) = w1;
  }
}

// ---------------- launcher ----------------
extern "C" void kernel_launch(void* const* d_in, const int* in_sizes, int n_in,
                              void* d_out, int out_size, void* d_ws, size_t ws_size,
                              hipStream_t stream) {
  (void)in_sizes; (void)n_in; (void)out_size; (void)ws_size;
  const float* hs   = (const float*)d_in[0];
  const float* wqkv = (const float*)d_in[1];
  const float* wd   = (const float*)d_in[2];
  float* out = (float*)d_out;

  char* ws = (char*)d_ws;
  size_t off = 0;
  auto alloc = [&](size_t b) -> char* {
    char* p = ws + off;
    off += (b + 255) & ~(size_t)255;
    return p;
  };
  bf16* Xb     = (bf16*)alloc((size_t)SEQ * HIDDEN * 2);
  bf16* Wqb    = (bf16*)alloc((size_t)QKV_PAD * HIDDEN * 2);   // zero-padded rows
  bf16* Wdb    = (bf16*)alloc((size_t)HID_PAD * HIDDEN * 2);   // zero-padded rows
  float* fused = (float*)alloc((size_t)SEQ * QKV_OUT * 4);
  bf16* Qb     = (bf16*)alloc((size_t)SEQ * HIDDEN * 2);
  bf16* Kf     = (bf16*)alloc((size_t)(SEQ / 16) * 1024 * 2);
  f16*  Vf     = (f16*)alloc((size_t)(SEQ / 16) * 1024 * 2);
  float* cs_tab = (float*)alloc((size_t)SEQ * 64 * 4);
  float* sn_tab = (float*)alloc((size_t)SEQ * 64 * 4);
  bf16* Ao     = (bf16*)fused;  // fused dead after rope/kvprep -> reuse

  const int NC4 = HIDDEN / 4;   // 1136
  {
    int n4 = SEQ * NC4;
    cvt_pad_k<<<(n4 + 255) / 256, 256, 0, stream>>>(hs, Xb, NC4, SEQ, n4);
    n4 = QKV_PAD * NC4;
    cvt_pad_k<<<(n4 + 255) / 256, 256, 0, stream>>>(wqkv, Wqb, NC4, QKV_OUT, n4);
    n4 = HID_PAD * NC4;
    cvt_pad_k<<<(n4 + 255) / 256, 256, 0, stream>>>(wd, Wdb, NC4, HIDDEN, n4);
  }
  gemm8p_k<<<dim3(SEQ / 256, QKV_PAD / 256), 512, 0, stream>>>(
      Xb, Wqb, fused, HIDDEN, QKV_OUT, QKV_OUT);
  rope_q_k<<<SEQ, 256, 0, stream>>>(fused, Qb, cs_tab, sn_tab);
  kvprep_k<<<SEQ / 16, 64, 0, stream>>>(fused, cs_tab, sn_tab, Kf, Vf);
  attn_k<<<dim3(SEQ / 32, NHEAD), 64, 0, stream>>>(Qb, Kf, Vf, Ao);
  gemm8p_k<<<dim3(SEQ / 256, HID_PAD / 256), 512, 0, stream>>>(
      Ao, Wdb, out, HIDDEN, HIDDEN, HIDDEN);
}

// Round 3
// 599.659 us; speedup vs baseline: 1.2545x; 1.0440x over previous
//
#include <hip/hip_runtime.h>

// ---- problem constants ----
#define SEQ     2048
#define HIDDEN  4544          // 71 * 64
#define NHEAD   71
#define HD      64
#define QKV_OUT 4672          // (71+2)*64
#define QKV_PAD 4800          // 25*192
#define HID_PAD 4608          // 24*192

typedef __bf16    bf16;
typedef _Float16  f16;
typedef __bf16    bf16x8 __attribute__((ext_vector_type(8)));
typedef __bf16    bf16x4 __attribute__((ext_vector_type(4)));
typedef _Float16  f16x4  __attribute__((ext_vector_type(4)));
typedef float     f32x4  __attribute__((ext_vector_type(4)));

// async global->LDS, 16B per lane. ldsbase must be wave-uniform; HW adds lane*16B.
__device__ inline void gl2lds16(const void* g, void* ldsbase) {
  __builtin_amdgcn_global_load_lds(
      (const __attribute__((address_space(1))) unsigned int*)g,
      (__attribute__((address_space(3))) unsigned int*)ldsbase,
      16, 0, 0);
}

// ---------------- fp32 -> bf16 convert, with zero row-padding ----------------
__global__ void cvt_pad_k(const float* __restrict__ in, bf16* __restrict__ out,
                          int ncols4, int nrows, int n4tot) {
  int i = blockIdx.x * blockDim.x + threadIdx.x;
  if (i >= n4tot) return;
  int row = i / ncols4;
  bf16x4 o;
  if (row < nrows) {
    float4 f = ((const float4*)in)[i];
    o[0] = (bf16)f.x; o[1] = (bf16)f.y; o[2] = (bf16)f.z; o[3] = (bf16)f.w;
  } else {
    o[0] = o[1] = o[2] = o[3] = (bf16)0.f;
  }
  *(bf16x4*)(out + (size_t)i * 4) = o;
}

// LDS tile layout (R rows x 64 cols bf16, st_16x32-style subtiled+swizzled):
// elem(R, ce) = (R>>4)*1024 + (ce>>5)*512 + (R&15)*32 + ((ce&31) ^ (((R>>3)&1)<<4))
__device__ inline int ldsaddr(int R, int ks, int grp) {
  return (R >> 4) * 1024 + ks * 512 + (R & 15) * 32 + ((grp * 8) ^ (((R >> 3) & 1) << 4));
}

// stage one 64-row chunk (8KB) of a tile: LDS dest LINEAR in thread order
// (HW requirement); source address carries the inverse swizzle (G21).
__device__ inline void stage64s(const bf16* mat, int gr0, int kc, int K,
                                bf16* region, int t, int w) {
  const int row = ((t >> 7) << 4) + ((t >> 2) & 15);
  const int ce  = (((t >> 6) & 1) << 5) + ((((t & 3) << 3)) ^ (((t >> 5) & 1) << 4));
  gl2lds16(mat + (size_t)(gr0 + row) * K + kc + ce, region + w * 512);
}

// ---------------- 4-phase pipelined bt-GEMM, 256x192 tile, deep prefetch ----
// C[M x Nmat] = A[M x K]*B[Npad x K]^T, M%256==0, K%64==0, B zero-row-padded to
// gridDim.y*192. 512 threads (8 waves 2Mx4N, per-wave 128x48). BK=64.
// A triple-buffered (stage kt+2 in ph0/ph1, no WAR constraint), B double-buffered
// (stage kt+2 in ph2/ph3 after reads drain). 7 wave-loads/K-tile; vmcnt(7) once
// per K-tile => issue->wait distance 4-6 phases for every chunk.
__global__ __launch_bounds__(512) void gemm8p_k(const bf16* __restrict__ A,
                                                const bf16* __restrict__ B,
                                                float* __restrict__ C,
                                                int K, int Nmat, int ldc) {
  __shared__ bf16 lA[3][256 * 64];   // 96 KiB
  __shared__ bf16 lB[2][192 * 64];   // 48 KiB
  const int t = threadIdx.x;
  const int lane = t & 63, w = t >> 6;
  const int qi = lane & 15, grp = lane >> 4;
  const int wm = w >> 2, wn = w & 3;

  // XCD-aware block swizzle (both call sites: nwg % 8 == 0)
  const int gx = gridDim.x;
  const int nwg = gx * gridDim.y;
  const int orig = blockIdx.y * gx + blockIdx.x;
  const int swz = (orig & 7) * (nwg >> 3) + (orig >> 3);
  const int m0 = (swz % gx) * 256;
  const int n0 = (swz / gx) * 192;

  const int NK = K >> 6;

  // prologue: A(0)->lA[0], B(0)->lB[0], A(1)->lA[1], B(1)->lB[1]  (14 loads)
  stage64s(A, m0 +   0, 0, K, &lA[0][0],     t, w);
  stage64s(A, m0 +  64, 0, K, &lA[0][4096],  t, w);
  stage64s(A, m0 + 128, 0, K, &lA[0][8192],  t, w);
  stage64s(A, m0 + 192, 0, K, &lA[0][12288], t, w);
  stage64s(B, n0 +   0, 0, K, &lB[0][0],     t, w);
  stage64s(B, n0 +  64, 0, K, &lB[0][4096],  t, w);
  stage64s(B, n0 + 128, 0, K, &lB[0][8192],  t, w);
  const int k1 = (NK > 1 ? 1 : 0) << 6;
  stage64s(A, m0 +   0, k1, K, &lA[1][0],     t, w);
  stage64s(A, m0 +  64, k1, K, &lA[1][4096],  t, w);
  stage64s(A, m0 + 128, k1, K, &lA[1][8192],  t, w);
  stage64s(A, m0 + 192, k1, K, &lA[1][12288], t, w);
  stage64s(B, n0 +   0, k1, K, &lB[1][0],     t, w);
  stage64s(B, n0 +  64, k1, K, &lB[1][4096],  t, w);
  stage64s(B, n0 + 128, k1, K, &lB[1][8192],  t, w);
  // tile 0 landed; tile 1's 7 loads may stay in flight
  asm volatile("s_waitcnt vmcnt(7)" ::: "memory");
  __builtin_amdgcn_s_barrier();

  f32x4 acc[8][3] = {};
  bf16x8 bb[3][2];
  int c3 = 0, s3 = 2;                // A read / A stage buffer indices (mod 3)

  for (int kt = 0; kt < NK; ++kt) {
    const int c2 = kt & 1;           // B read buffer; also B stage target (kt+2)
    const int kf = (kt + 2 < NK ? kt + 2 : NK - 1) << 6;
    bf16* curA = &lA[c3][0];
    bf16* curB = &lB[c2][0];
    bf16* stgA = &lA[s3][0];
    bf16* stgB = &lB[c2][0];
    bf16x8 af[4];

    // ---- phase 0 (mh0, ks0): read a x4 + b(:,0) x3; stage A(kt+2) ch0,1 ----
#pragma unroll
    for (int i = 0; i < 4; ++i)
      af[i] = *(const bf16x8*)&curA[ldsaddr(wm * 128 + i * 16 + qi, 0, grp)];
#pragma unroll
    for (int j = 0; j < 3; ++j)
      bb[j][0] = *(const bf16x8*)&curB[ldsaddr(wn * 48 + j * 16 + qi, 0, grp)];
    stage64s(A, m0 +  0, kf, K, stgA,        t, w);
    stage64s(A, m0 + 64, kf, K, stgA + 4096, t, w);
    asm volatile("" ::: "memory");
    __builtin_amdgcn_s_barrier();
    asm volatile("s_waitcnt lgkmcnt(0)" ::: "memory");
    __builtin_amdgcn_s_setprio(1);
#pragma unroll
    for (int i = 0; i < 4; ++i)
#pragma unroll
      for (int j = 0; j < 3; ++j)
        acc[i][j] = __builtin_amdgcn_mfma_f32_16x16x32_bf16(af[i], bb[j][0], acc[i][j], 0, 0, 0);
    __builtin_amdgcn_s_setprio(0);
    __builtin_amdgcn_s_barrier();

    // ---- phase 1 (mh0, ks1): read a x4 + b(:,1) x3; stage A(kt+2) ch2,3 ----
#pragma unroll
    for (int i = 0; i < 4; ++i)
      af[i] = *(const bf16x8*)&curA[ldsaddr(wm * 128 + i * 16 + qi, 1, grp)];
#pragma unroll
    for (int j = 0; j < 3; ++j)
      bb[j][1] = *(const bf16x8*)&curB[ldsaddr(wn * 48 + j * 16 + qi, 1, grp)];
    stage64s(A, m0 + 128, kf, K, stgA + 8192,  t, w);
    stage64s(A, m0 + 192, kf, K, stgA + 12288, t, w);
    asm volatile("" ::: "memory");
    __builtin_amdgcn_s_barrier();
    asm volatile("s_waitcnt lgkmcnt(0)" ::: "memory");
    __builtin_amdgcn_s_setprio(1);
#pragma unroll
    for (int i = 0; i < 4; ++i)
#pragma unroll
      for (int j = 0; j < 3; ++j)
        acc[i][j] = __builtin_amdgcn_mfma_f32_16x16x32_bf16(af[i], bb[j][1], acc[i][j], 0, 0, 0);
    __builtin_amdgcn_s_setprio(0);
    __builtin_amdgcn_s_barrier();

    // ---- phase 2 (mh1, ks0): read a x4; stage B(kt+2) ch0,1 (reads drained ph1) ----
#pragma unroll
    for (int i = 0; i < 4; ++i)
      af[i] = *(const bf16x8*)&curA[ldsaddr(wm * 128 + 64 + i * 16 + qi, 0, grp)];
    stage64s(B, n0 +  0, kf, K, stgB,        t, w);
    stage64s(B, n0 + 64, kf, K, stgB + 4096, t, w);
    asm volatile("" ::: "memory");
    __builtin_amdgcn_s_barrier();
    asm volatile("s_waitcnt lgkmcnt(0)" ::: "memory");
    __builtin_amdgcn_s_setprio(1);
#pragma unroll
    for (int i = 0; i < 4; ++i)
#pragma unroll
      for (int j = 0; j < 3; ++j)
        acc[4 + i][j] = __builtin_amdgcn_mfma_f32_16x16x32_bf16(af[i], bb[j][0], acc[4 + i][j], 0, 0, 0);
    __builtin_amdgcn_s_setprio(0);
    __builtin_amdgcn_s_barrier();

    // ---- phase 3 (mh1, ks1): read a x4; stage B(kt+2) ch2; vmcnt(7) ----
    // ledger: issued = 14 + 7*(kt+1); vmcnt(7) => tiles <= kt+1 fully landed.
#pragma unroll
    for (int i = 0; i < 4; ++i)
      af[i] = *(const bf16x8*)&curA[ldsaddr(wm * 128 + 64 + i * 16 + qi, 1, grp)];
    stage64s(B, n0 + 128, kf, K, stgB + 8192, t, w);
    asm volatile("s_waitcnt vmcnt(7)" ::: "memory");
    __builtin_amdgcn_s_barrier();
    asm volatile("s_waitcnt lgkmcnt(0)" ::: "memory");
    __builtin_amdgcn_s_setprio(1);
#pragma unroll
    for (int i = 0; i < 4; ++i)
#pragma unroll
      for (int j = 0; j < 3; ++j)
        acc[4 + i][j] = __builtin_amdgcn_mfma_f32_16x16x32_bf16(af[i], bb[j][1], acc[4 + i][j], 0, 0, 0);
    __builtin_amdgcn_s_setprio(0);
    __builtin_amdgcn_s_barrier();

    c3 = (c3 == 2) ? 0 : c3 + 1;
    s3 = (s3 == 2) ? 0 : s3 + 1;
  }

  // ---- epilogue: C-write (cols >= Nmat come from zero-padded B rows; guarded) ----
#pragma unroll
  for (int i = 0; i < 8; ++i) {
    const int row = m0 + wm * 128 + (i >> 2) * 64 + (i & 3) * 16 + grp * 4;
#pragma unroll
    for (int j = 0; j < 3; ++j) {
      const int col = n0 + wn * 48 + j * 16 + qi;
      if (col < Nmat) {
#pragma unroll
        for (int r = 0; r < 4; ++r)
          C[(size_t)(row + r) * ldc + col] = acc[i][j][r];
      }
    }
  }
}

// ---------------- RoPE for Q (scale 1/8 folded in) + cos/sin tables ----------------
__global__ __launch_bounds__(256) void rope_q_k(const float* __restrict__ fused,
                                                bf16* __restrict__ Qb,
                                                float* __restrict__ cs_tab,
                                                float* __restrict__ sn_tab) {
  const int s = blockIdx.x, t = threadIdx.x;
  __shared__ float cs[64], sn[64];
  if (t < 64) {
    int i = t & 31;
    double invf = pow(10000.0, -(double)i / 32.0);
    double ang = (double)s * invf;
    float c = (float)cos(ang), n = (float)sin(ang);
    cs[t] = c; sn[t] = n;
    cs_tab[s * 64 + t] = c;
    sn_tab[s * 64 + t] = n;
  }
  __syncthreads();
  const float* row = fused + (size_t)s * QKV_OUT;
  for (int e = t; e < HIDDEN; e += 256) {
    int d = e & 63;
    float x = row[e], xp = row[e ^ 32];
    float rot = (d < 32) ? -xp : xp;
    Qb[(size_t)s * HIDDEN + e] = (bf16)((x * cs[d] + rot * sn[d]) * 0.125f);
  }
}

// ---------------- K (roped) and V -> MFMA-operand-ordered global layouts ----------------
__global__ __launch_bounds__(64) void kvprep_k(const float* __restrict__ fused,
                                               const float* __restrict__ cs_tab,
                                               const float* __restrict__ sn_tab,
                                               bf16* __restrict__ Kf,
                                               f16* __restrict__ Vf) {
  const int t16 = blockIdx.x, lane = threadIdx.x;
  const int qi = lane & 15, grp = lane >> 4;
  const int s = t16 * 16 + qi;
  const float* krow = fused + (size_t)s * QKV_OUT + NHEAD * 64;
  const float* cs = cs_tab + s * 64;
  const float* sn = sn_tab + s * 64;
#pragma unroll
  for (int half = 0; half < 2; ++half) {
    bf16x8 o;
    const int d0 = half * 32 + grp * 8;
#pragma unroll
    for (int j = 0; j < 8; ++j) {
      int d = d0 + j;
      float x = krow[d], xp = krow[d ^ 32];
      float rot = (d < 32) ? -xp : xp;
      o[j] = (bf16)(x * cs[d] + rot * sn[d]);
    }
    *(bf16x8*)&Kf[(t16 * 2 + half) * 512 + lane * 8] = o;
  }
#pragma unroll
  for (int tt = 0; tt < 4; ++tt) {
    f16x4 o;
#pragma unroll
    for (int j = 0; j < 4; ++j)
      o[j] = (f16)fused[(size_t)(t16 * 16 + grp * 4 + j) * QKV_OUT + (NHEAD + 1) * 64 + tt * 16 + qi];
    *(f16x4*)&Vf[t16 * 1024 + tt * 256 + lane * 4] = o;
  }
}

// ---------------- causal MQA flash attention: 1 wave = (head, 32 q rows) ----------------
__global__ __launch_bounds__(64) void attn_k(const bf16* __restrict__ Qb,
                                             const bf16* __restrict__ Kf,
                                             const f16*  __restrict__ Vf,
                                             bf16* __restrict__ Ao) {
  __shared__ float fl[2 * 16 * 68];
  const int h = blockIdx.y;
  const int b32 = gridDim.x - 1 - blockIdx.x;   // big blocks first
  const int lane = threadIdx.x;
  const int qi = lane & 15, grp = lane >> 4;
  const int q0 = b32 * 32;
  const int lastT = b32 >> 1;

  bf16x8 qf[2][2];
#pragma unroll
  for (int qq = 0; qq < 2; ++qq) {
    const bf16* qb = Qb + (size_t)(q0 + qq * 16 + qi) * HIDDEN + h * 64 + grp * 8;
    qf[qq][0] = *(const bf16x8*)qb;
    qf[qq][1] = *(const bf16x8*)(qb + 32);
  }

  f32x4 o[2][4] = {};
  float l[2] = {0.f, 0.f};

  for (int kb = 0; kb <= lastT; ++kb) {
    const bf16* kfp = Kf + (size_t)kb * 4096 + lane * 8;
    bf16x8 kf[4][2];
#pragma unroll
    for (int kk = 0; kk < 4; ++kk) {
      kf[kk][0] = *(const bf16x8*)(kfp + kk * 1024);
      kf[kk][1] = *(const bf16x8*)(kfp + kk * 1024 + 512);
    }
    f32x4 s4[2][4];
#pragma unroll
    for (int qq = 0; qq < 2; ++qq)
#pragma unroll
      for (int kk = 0; kk < 4; ++kk) {
        f32x4 z = {};
        s4[qq][kk] = __builtin_amdgcn_mfma_f32_16x16x32_bf16(kf[kk][0], qf[qq][0], z, 0, 0, 0);
        s4[qq][kk] = __builtin_amdgcn_mfma_f32_16x16x32_bf16(kf[kk][1], qf[qq][1], s4[qq][kk], 0, 0, 0);
      }
    const f16* vfp = Vf + (size_t)kb * 4096 + lane * 4;
    f16x4 vf[4][4];
#pragma unroll
    for (int kk = 0; kk < 4; ++kk)
#pragma unroll
      for (int tt = 0; tt < 4; ++tt)
        vf[kk][tt] = *(const f16x4*)(vfp + kk * 1024 + tt * 256);

    if (kb == lastT) {
      const int dq = q0 - kb * 64 + qi;
#pragma unroll
      for (int qq = 0; qq < 2; ++qq)
#pragma unroll
        for (int kk = 0; kk < 4; ++kk)
#pragma unroll
          for (int r = 0; r < 4; ++r)
            if (kk * 16 + grp * 4 + r > dq + qq * 16) s4[qq][kk][r] = -1e30f;
    }
    f16x4 pf[2][4];
#pragma unroll
    for (int qq = 0; qq < 2; ++qq) {
      float ls = 0.f;
#pragma unroll
      for (int kk = 0; kk < 4; ++kk) {
        float p0 = __expf(s4[qq][kk][0]), p1 = __expf(s4[qq][kk][1]);
        float p2 = __expf(s4[qq][kk][2]), p3 = __expf(s4[qq][kk][3]);
        ls += (p0 + p1) + (p2 + p3);
        pf[qq][kk][0] = (f16)p0; pf[qq][kk][1] = (f16)p1;
        pf[qq][kk][2] = (f16)p2; pf[qq][kk][3] = (f16)p3;
      }
      l[qq] += ls;
    }
#pragma unroll
    for (int qq = 0; qq < 2; ++qq)
#pragma unroll
      for (int tt = 0; tt < 4; ++tt)
#pragma unroll
        for (int kk = 0; kk < 4; ++kk)
          o[qq][tt] = __builtin_amdgcn_mfma_f32_16x16x16f16(pf[qq][kk], vf[kk][tt], o[qq][tt], 0, 0, 0);
  }

#pragma unroll
  for (int qq = 0; qq < 2; ++qq) {
    float lq = l[qq];
    lq += __shfl_xor(lq, 16);
    lq += __shfl_xor(lq, 32);
    const float inv = 1.0f / lq;
    const float i0 = __shfl(inv, grp * 4 + 0);
    const float i1 = __shfl(inv, grp * 4 + 1);
    const float i2 = __shfl(inv, grp * 4 + 2);
    const float i3 = __shfl(inv, grp * 4 + 3);
    float* flq = fl + qq * 1088;
#pragma unroll
    for (int tt = 0; tt < 4; ++tt) {
      flq[(grp * 4 + 0) * 68 + tt * 16 + qi] = o[qq][tt][0] * i0;
      flq[(grp * 4 + 1) * 68 + tt * 16 + qi] = o[qq][tt][1] * i1;
      flq[(grp * 4 + 2) * 68 + tt * 16 + qi] = o[qq][tt][2] * i2;
      flq[(grp * 4 + 3) * 68 + tt * 16 + qi] = o[qq][tt][3] * i3;
    }
  }
  __syncthreads();
  const int row = lane >> 2, c0 = (lane & 3) * 16;
#pragma unroll
  for (int qq = 0; qq < 2; ++qq) {
    const float* flq = fl + qq * 1088;
    bf16x8 w0, w1;
#pragma unroll
    for (int j = 0; j < 8; ++j) {
      w0[j] = (bf16)flq[row * 68 + c0 + j];
      w1[j] = (bf16)flq[row * 68 + c0 + 8 + j];
    }
    bf16* ob = Ao + (size_t)(q0 + qq * 16 + row) * HIDDEN + h * 64 + c0;
    *(bf16x8*)ob = w0;
    *(bf16x8*)(ob + 8) = w1;
  }
}

// ---------------- launcher ----------------
extern "C" void kernel_launch(void* const* d_in, const int* in_sizes, int n_in,
                              void* d_out, int out_size, void* d_ws, size_t ws_size,
                              hipStream_t stream) {
  (void)in_sizes; (void)n_in; (void)out_size; (void)ws_size;
  const float* hs   = (const float*)d_in[0];
  const float* wqkv = (const float*)d_in[1];
  const float* wd   = (const float*)d_in[2];
  float* out = (float*)d_out;

  char* ws = (char*)d_ws;
  size_t off = 0;
  auto alloc = [&](size_t b) -> char* {
    char* p = ws + off;
    off += (b + 255) & ~(size_t)255;
    return p;
  };
  bf16* Xb     = (bf16*)alloc((size_t)SEQ * HIDDEN * 2);
  bf16* Wqb    = (bf16*)alloc((size_t)QKV_PAD * HIDDEN * 2);   // zero-padded rows
  bf16* Wdb    = (bf16*)alloc((size_t)HID_PAD * HIDDEN * 2);   // zero-padded rows
  float* fused = (float*)alloc((size_t)SEQ * QKV_OUT * 4);
  bf16* Qb     = (bf16*)alloc((size_t)SEQ * HIDDEN * 2);
  bf16* Kf     = (bf16*)alloc((size_t)(SEQ / 16) * 1024 * 2);
  f16*  Vf     = (f16*)alloc((size_t)(SEQ / 16) * 1024 * 2);
  float* cs_tab = (float*)alloc((size_t)SEQ * 64 * 4);
  float* sn_tab = (float*)alloc((size_t)SEQ * 64 * 4);
  bf16* Ao     = (bf16*)fused;  // fused dead after rope/kvprep -> reuse

  const int NC4 = HIDDEN / 4;   // 1136
  {
    int n4 = SEQ * NC4;
    cvt_pad_k<<<(n4 + 255) / 256, 256, 0, stream>>>(hs, Xb, NC4, SEQ, n4);
    n4 = QKV_PAD * NC4;
    cvt_pad_k<<<(n4 + 255) / 256, 256, 0, stream>>>(wqkv, Wqb, NC4, QKV_OUT, n4);
    n4 = HID_PAD * NC4;
    cvt_pad_k<<<(n4 + 255) / 256, 256, 0, stream>>>(wd, Wdb, NC4, HIDDEN, n4);
  }
  gemm8p_k<<<dim3(SEQ / 256, QKV_PAD / 192), 512, 0, stream>>>(
      Xb, Wqb, fused, HIDDEN, QKV_OUT, QKV_OUT);
  rope_q_k<<<SEQ, 256, 0, stream>>>(fused, Qb, cs_tab, sn_tab);
  kvprep_k<<<SEQ / 16, 64, 0, stream>>>(fused, cs_tab, sn_tab, Kf, Vf);
  attn_k<<<dim3(SEQ / 32, NHEAD), 64, 0, stream>>>(Qb, Kf, Vf, Ao);
  gemm8p_k<<<dim3(SEQ / 256, HID_PAD / 192), 512, 0, stream>>>(
      Ao, Wdb, out, HIDDEN, HIDDEN, HIDDEN);
}

// Round 4
// 550.021 us; speedup vs baseline: 1.3677x; 1.0902x over previous
//
#include <hip/hip_runtime.h>

// ---- problem constants ----
#define SEQ     2048
#define HIDDEN  4544          // 71 * 64
#define NHEAD   71
#define HD      64
#define QKV_OUT 4672          // (71+2)*64

typedef __bf16    bf16;
typedef _Float16  f16;
typedef __bf16    bf16x8 __attribute__((ext_vector_type(8)));
typedef __bf16    bf16x4 __attribute__((ext_vector_type(4)));
typedef _Float16  f16x4  __attribute__((ext_vector_type(4)));
typedef _Float16  f16x8  __attribute__((ext_vector_type(8)));
typedef float     f32x4  __attribute__((ext_vector_type(4)));

// async global->LDS, 16B per lane. ldsbase must be wave-uniform; HW adds lane*16B.
__device__ inline void gl2lds16(const void* g, void* ldsbase) {
  __builtin_amdgcn_global_load_lds(
      (const __attribute__((address_space(1))) unsigned int*)g,
      (__attribute__((address_space(3))) unsigned int*)ldsbase,
      16, 0, 0);
}

// ---------------- fp32 -> bf16 convert (vectorized) ----------------
__global__ void cvt_f32_bf16_k(const float* __restrict__ in, bf16* __restrict__ out, int n4) {
  int i = blockIdx.x * blockDim.x + threadIdx.x;
  if (i >= n4) return;
  float4 f = ((const float4*)in)[i];
  bf16x4 o;
  o[0] = (bf16)f.x; o[1] = (bf16)f.y; o[2] = (bf16)f.z; o[3] = (bf16)f.w;
  *(bf16x4*)(out + (size_t)i * 4) = o;
}

// ---------------- bt-GEMM, BK=64: C[M x Nmat] = A[M x K] * B[Nmat x K]^T ----------------
// 128x128 C-tile, 256 threads (4 waves, 2x2 of 64x64). Two m97-style 32-wide k-slices
// staged per barrier pair. Round-0 proven structure + T1 XCD-aware block swizzle:
// consecutive blocks on one XCD share the same 128-col B panel (L2-resident, 1.16 MB)
// and walk m within it -> cuts the 3.2x HBM over-fetch (197 MB vs 62 MB unique A+B).
__global__ __launch_bounds__(256) void gemm_bt_k(const bf16* __restrict__ A,
                                                 const bf16* __restrict__ B,
                                                 float* __restrict__ C,
                                                 int K, int Nmat, int ldc) {
  __shared__ bf16 lA[2][128 * 32];   // [k-half][row*32 + k]
  __shared__ bf16 lB[2][128 * 32];
  const int t = threadIdx.x;
  const int lane = t & 63, w = t >> 6;

  // T1: bijective XCD swizzle (both call sites have nwg % 8 == 0)
  const int gx = gridDim.x;
  const int nwg = gx * gridDim.y;
  const int orig = blockIdx.y * gx + blockIdx.x;
  const int swz = (orig & 7) * (nwg >> 3) + (orig >> 3);
  const int m0 = (swz % gx) * 128;
  const int n0 = (swz / gx) * 128;

  const int wm = (w >> 1) * 64, wn = (w & 1) * 64;
  const int qi = lane & 15, grp = lane >> 4;

  const int r0 = t >> 2;            // 0..63: row within 64-row block
  const int c0 = (t & 3) * 8;       // 0,8,16,24: k offset within 32-slice
  const bf16* gA0 = A + (size_t)(m0 + r0) * K + c0;
  const bf16* gA1 = A + (size_t)(m0 + 64 + r0) * K + c0;
  int bR0 = n0 + r0;      if (bR0 >= Nmat) bR0 = Nmat - 1;
  int bR1 = n0 + 64 + r0; if (bR1 >= Nmat) bR1 = Nmat - 1;
  const bf16* gB0 = B + (size_t)bR0 * K + c0;
  const bf16* gB1 = B + (size_t)bR1 * K + c0;
  bf16* lA00 = &lA[0][0] + w * 512;          // (half0, rows 0-63)
  bf16* lA01 = &lA[0][2048] + w * 512;       // (half0, rows 64-127)
  bf16* lA10 = &lA[1][0] + w * 512;
  bf16* lA11 = &lA[1][2048] + w * 512;
  bf16* lB00 = &lB[0][0] + w * 512;
  bf16* lB01 = &lB[0][2048] + w * 512;
  bf16* lB10 = &lB[1][0] + w * 512;
  bf16* lB11 = &lB[1][2048] + w * 512;

  f32x4 acc[4][4] = {};
  for (int k0 = 0; k0 < K; k0 += 64) {
    __syncthreads();
    gl2lds16(gA0 + k0,      lA00);
    gl2lds16(gA1 + k0,      lA01);
    gl2lds16(gA0 + k0 + 32, lA10);
    gl2lds16(gA1 + k0 + 32, lA11);
    gl2lds16(gB0 + k0,      lB00);
    gl2lds16(gB1 + k0,      lB01);
    gl2lds16(gB0 + k0 + 32, lB10);
    gl2lds16(gB1 + k0 + 32, lB11);
    __syncthreads();
#pragma unroll
    for (int half = 0; half < 2; ++half) {
      bf16x8 af[4], bfv[4];
#pragma unroll
      for (int i = 0; i < 4; ++i)
        af[i] = *(const bf16x8*)&lA[half][(wm + i * 16 + qi) * 32 + grp * 8];
#pragma unroll
      for (int i = 0; i < 4; ++i)
        bfv[i] = *(const bf16x8*)&lB[half][(wn + i * 16 + qi) * 32 + grp * 8];
#pragma unroll
      for (int i = 0; i < 4; ++i)
#pragma unroll
        for (int j = 0; j < 4; ++j)
          acc[i][j] = __builtin_amdgcn_mfma_f32_16x16x32_bf16(af[i], bfv[j], acc[i][j], 0, 0, 0);
    }
  }

#pragma unroll
  for (int i = 0; i < 4; ++i) {
    const int row = m0 + wm + i * 16 + grp * 4;
#pragma unroll
    for (int j = 0; j < 4; ++j) {
      const int col = n0 + wn + j * 16 + qi;
      if (col < Nmat) {
#pragma unroll
        for (int r = 0; r < 4; ++r)
          C[(size_t)(row + r) * ldc + col] = acc[i][j][r];
      }
    }
  }
}

// ---------------- RoPE for Q (scale 1/8 folded in) + cos/sin tables ----------------
__global__ __launch_bounds__(256) void rope_q_k(const float* __restrict__ fused,
                                                bf16* __restrict__ Qb,
                                                float* __restrict__ cs_tab,
                                                float* __restrict__ sn_tab) {
  const int s = blockIdx.x, t = threadIdx.x;
  __shared__ float cs[64], sn[64];
  if (t < 64) {
    int i = t & 31;
    double invf = pow(10000.0, -(double)i / 32.0);
    double ang = (double)s * invf;
    float c = (float)cos(ang), n = (float)sin(ang);
    cs[t] = c; sn[t] = n;
    cs_tab[s * 64 + t] = c;
    sn_tab[s * 64 + t] = n;
  }
  __syncthreads();
  const float* row = fused + (size_t)s * QKV_OUT;
  for (int e = t; e < HIDDEN; e += 256) {
    int d = e & 63;
    float x = row[e], xp = row[e ^ 32];
    float rot = (d < 32) ? -xp : xp;
    Qb[(size_t)s * HIDDEN + e] = (bf16)((x * cs[d] + rot * sn[d]) * 0.125f);
  }
}

// ---------------- K (roped) and V -> MFMA-operand-ordered global layouts ----------------
// Vf layout pairs tt-subtiles so attention reads V as 16B/lane:
// elem(kv = t16*16+grp*4+j, d = tt*16+qi) at t16*1024 + (tt>>1)*512 + lane*8 + (tt&1)*4 + j
__global__ __launch_bounds__(64) void kvprep_k(const float* __restrict__ fused,
                                               const float* __restrict__ cs_tab,
                                               const float* __restrict__ sn_tab,
                                               bf16* __restrict__ Kf,
                                               f16* __restrict__ Vf) {
  const int t16 = blockIdx.x, lane = threadIdx.x;
  const int qi = lane & 15, grp = lane >> 4;
  const int s = t16 * 16 + qi;
  const float* krow = fused + (size_t)s * QKV_OUT + NHEAD * 64;
  const float* cs = cs_tab + s * 64;
  const float* sn = sn_tab + s * 64;
#pragma unroll
  for (int half = 0; half < 2; ++half) {
    bf16x8 o;
    const int d0 = half * 32 + grp * 8;
#pragma unroll
    for (int j = 0; j < 8; ++j) {
      int d = d0 + j;
      float x = krow[d], xp = krow[d ^ 32];
      float rot = (d < 32) ? -xp : xp;
      o[j] = (bf16)(x * cs[d] + rot * sn[d]);
    }
    *(bf16x8*)&Kf[(t16 * 2 + half) * 512 + lane * 8] = o;
  }
#pragma unroll
  for (int p = 0; p < 2; ++p) {
    f16x8 o;
#pragma unroll
    for (int h = 0; h < 2; ++h) {
      const int tt = p * 2 + h;
#pragma unroll
      for (int j = 0; j < 4; ++j)
        o[h * 4 + j] = (f16)fused[(size_t)(t16 * 16 + grp * 4 + j) * QKV_OUT + (NHEAD + 1) * 64 + tt * 16 + qi];
    }
    *(f16x8*)&Vf[t16 * 1024 + p * 512 + lane * 8] = o;
  }
}

// ---------------- causal MQA flash attention: 1 wave = (head, 32 q rows) ----------------
__global__ __launch_bounds__(64) void attn_k(const bf16* __restrict__ Qb,
                                             const bf16* __restrict__ Kf,
                                             const f16*  __restrict__ Vf,
                                             bf16* __restrict__ Ao) {
  __shared__ float fl[2 * 16 * 68];
  const int h = blockIdx.y;
  const int b32 = gridDim.x - 1 - blockIdx.x;   // big blocks first
  const int lane = threadIdx.x;
  const int qi = lane & 15, grp = lane >> 4;
  const int q0 = b32 * 32;
  const int lastT = b32 >> 1;

  bf16x8 qf[2][2];
#pragma unroll
  for (int qq = 0; qq < 2; ++qq) {
    const bf16* qb = Qb + (size_t)(q0 + qq * 16 + qi) * HIDDEN + h * 64 + grp * 8;
    qf[qq][0] = *(const bf16x8*)qb;
    qf[qq][1] = *(const bf16x8*)(qb + 32);
  }

  f32x4 o[2][4] = {};
  float l[2] = {0.f, 0.f};

  for (int kb = 0; kb <= lastT; ++kb) {
    const bf16* kfp = Kf + (size_t)kb * 4096 + lane * 8;
    bf16x8 kf[4][2];
#pragma unroll
    for (int kk = 0; kk < 4; ++kk) {
      kf[kk][0] = *(const bf16x8*)(kfp + kk * 1024);
      kf[kk][1] = *(const bf16x8*)(kfp + kk * 1024 + 512);
    }
    f32x4 s4[2][4];
#pragma unroll
    for (int qq = 0; qq < 2; ++qq)
#pragma unroll
      for (int kk = 0; kk < 4; ++kk) {
        f32x4 z = {};
        s4[qq][kk] = __builtin_amdgcn_mfma_f32_16x16x32_bf16(kf[kk][0], qf[qq][0], z, 0, 0, 0);
        s4[qq][kk] = __builtin_amdgcn_mfma_f32_16x16x32_bf16(kf[kk][1], qf[qq][1], s4[qq][kk], 0, 0, 0);
      }
    // V: 8 x 16B loads (paired-tt layout)
    const f16* vfp = Vf + (size_t)kb * 4096 + lane * 8;
    f16x4 vf[4][4];
#pragma unroll
    for (int kk = 0; kk < 4; ++kk)
#pragma unroll
      for (int p = 0; p < 2; ++p) {
        f16x8 v8 = *(const f16x8*)(vfp + kk * 1024 + p * 512);
#pragma unroll
        for (int j = 0; j < 4; ++j) {
          vf[kk][2 * p][j]     = v8[j];
          vf[kk][2 * p + 1][j] = v8[4 + j];
        }
      }

    if (kb == lastT) {
      const int dq = q0 - kb * 64 + qi;
#pragma unroll
      for (int qq = 0; qq < 2; ++qq)
#pragma unroll
        for (int kk = 0; kk < 4; ++kk)
#pragma unroll
          for (int r = 0; r < 4; ++r)
            if (kk * 16 + grp * 4 + r > dq + qq * 16) s4[qq][kk][r] = -1e30f;
    }
    f16x4 pf[2][4];
#pragma unroll
    for (int qq = 0; qq < 2; ++qq) {
      float ls = 0.f;
#pragma unroll
      for (int kk = 0; kk < 4; ++kk) {
        float p0 = __expf(s4[qq][kk][0]), p1 = __expf(s4[qq][kk][1]);
        float p2 = __expf(s4[qq][kk][2]), p3 = __expf(s4[qq][kk][3]);
        ls += (p0 + p1) + (p2 + p3);
        pf[qq][kk][0] = (f16)p0; pf[qq][kk][1] = (f16)p1;
        pf[qq][kk][2] = (f16)p2; pf[qq][kk][3] = (f16)p3;
      }
      l[qq] += ls;
    }
#pragma unroll
    for (int qq = 0; qq < 2; ++qq)
#pragma unroll
      for (int tt = 0; tt < 4; ++tt)
#pragma unroll
        for (int kk = 0; kk < 4; ++kk)
          o[qq][tt] = __builtin_amdgcn_mfma_f32_16x16x16f16(pf[qq][kk], vf[kk][tt], o[qq][tt], 0, 0, 0);
  }

#pragma unroll
  for (int qq = 0; qq < 2; ++qq) {
    float lq = l[qq];
    lq += __shfl_xor(lq, 16);
    lq += __shfl_xor(lq, 32);
    const float inv = 1.0f / lq;
    const float i0 = __shfl(inv, grp * 4 + 0);
    const float i1 = __shfl(inv, grp * 4 + 1);
    const float i2 = __shfl(inv, grp * 4 + 2);
    const float i3 = __shfl(inv, grp * 4 + 3);
    float* flq = fl + qq * 1088;
#pragma unroll
    for (int tt = 0; tt < 4; ++tt) {
      flq[(grp * 4 + 0) * 68 + tt * 16 + qi] = o[qq][tt][0] * i0;
      flq[(grp * 4 + 1) * 68 + tt * 16 + qi] = o[qq][tt][1] * i1;
      flq[(grp * 4 + 2) * 68 + tt * 16 + qi] = o[qq][tt][2] * i2;
      flq[(grp * 4 + 3) * 68 + tt * 16 + qi] = o[qq][tt][3] * i3;
    }
  }
  __syncthreads();
  const int row = lane >> 2, c0 = (lane & 3) * 16;
#pragma unroll
  for (int qq = 0; qq < 2; ++qq) {
    const float* flq = fl + qq * 1088;
    bf16x8 w0, w1;
#pragma unroll
    for (int j = 0; j < 8; ++j) {
      w0[j] = (bf16)flq[row * 68 + c0 + j];
      w1[j] = (bf16)flq[row * 68 + c0 + 8 + j];
    }
    bf16* ob = Ao + (size_t)(q0 + qq * 16 + row) * HIDDEN + h * 64 + c0;
    *(bf16x8*)ob = w0;
    *(bf16x8*)(ob + 8) = w1;
  }
}

// ---------------- launcher ----------------
extern "C" void kernel_launch(void* const* d_in, const int* in_sizes, int n_in,
                              void* d_out, int out_size, void* d_ws, size_t ws_size,
                              hipStream_t stream) {
  (void)in_sizes; (void)n_in; (void)out_size; (void)ws_size;
  const float* hs   = (const float*)d_in[0];
  const float* wqkv = (const float*)d_in[1];
  const float* wd   = (const float*)d_in[2];
  float* out = (float*)d_out;

  char* ws = (char*)d_ws;
  size_t off = 0;
  auto alloc = [&](size_t b) -> char* {
    char* p = ws + off;
    off += (b + 255) & ~(size_t)255;
    return p;
  };
  bf16* Xb     = (bf16*)alloc((size_t)SEQ * HIDDEN * 2);
  bf16* Wqb    = (bf16*)alloc((size_t)QKV_OUT * HIDDEN * 2);
  bf16* Wdb    = (bf16*)alloc((size_t)HIDDEN * HIDDEN * 2);
  float* fused = (float*)alloc((size_t)SEQ * QKV_OUT * 4);
  bf16* Qb     = (bf16*)alloc((size_t)SEQ * HIDDEN * 2);
  bf16* Kf     = (bf16*)alloc((size_t)(SEQ / 16) * 1024 * 2);
  f16*  Vf     = (f16*)alloc((size_t)(SEQ / 16) * 1024 * 2);
  float* cs_tab = (float*)alloc((size_t)SEQ * 64 * 4);
  float* sn_tab = (float*)alloc((size_t)SEQ * 64 * 4);
  bf16* Ao     = (bf16*)fused;  // fused dead after rope/kvprep -> reuse

  {
    int n4 = SEQ * HIDDEN / 4;
    cvt_f32_bf16_k<<<(n4 + 255) / 256, 256, 0, stream>>>(hs, Xb, n4);
    n4 = QKV_OUT * HIDDEN / 4;
    cvt_f32_bf16_k<<<(n4 + 255) / 256, 256, 0, stream>>>(wqkv, Wqb, n4);
    n4 = HIDDEN * HIDDEN / 4;
    cvt_f32_bf16_k<<<(n4 + 255) / 256, 256, 0, stream>>>(wd, Wdb, n4);
  }
  gemm_bt_k<<<dim3(SEQ / 128, (QKV_OUT + 127) / 128), 256, 0, stream>>>(
      Xb, Wqb, fused, HIDDEN, QKV_OUT, QKV_OUT);
  rope_q_k<<<SEQ, 256, 0, stream>>>(fused, Qb, cs_tab, sn_tab);
  kvprep_k<<<SEQ / 16, 64, 0, stream>>>(fused, cs_tab, sn_tab, Kf, Vf);
  attn_k<<<dim3(SEQ / 32, NHEAD), 64, 0, stream>>>(Qb, Kf, Vf, Ao);
  gemm_bt_k<<<dim3(SEQ / 128, (HIDDEN + 127) / 128), 256, 0, stream>>>(
      Ao, Wdb, out, HIDDEN, HIDDEN, HIDDEN);
}